// Round 14
// baseline (295.076 us; speedup 1.0000x reference)
//
#include <hip/hip_runtime.h>
#include <hip/hip_bf16.h>

// GCN: embed -> (conv -> bn -> relu) x2 -> conv(+relu+pool fused) -> linear
// H = 64.
// R13: (a) CSR entries = ushort (N<65536) written with nontemporal stores
//      (R12 counters: write amplification is per-STORE line writeback, 66B/
//      store). (b) conv gather unrolled to 4 batches / 32 slots in flight
//      (avg deg 16 -> one iteration, 4 gathers deep MLP).

// bf16 helpers
__device__ __forceinline__ unsigned short f2bf(float f) {
    unsigned int x = (unsigned int)__float_as_int(f);
    x += 0x7fffu + ((x >> 16) & 1u);
    return (unsigned short)(x >> 16);
}

// ---------- tiny precompute: fold one-hot/numeric linears through Wg0 ----------
__global__ void precompute_mats(const float* __restrict__ W1, const float* __restrict__ b1,
                                const float* __restrict__ W2, const float* __restrict__ b2,
                                const float* __restrict__ Wg0,
                                float* __restrict__ M1, float* __restrict__ M2,
                                float* __restrict__ cvec, int T) {
    int tid = threadIdx.x;
    for (int idx = tid; idx < T * 64; idx += blockDim.x) {
        int t = idx >> 6, c = idx & 63;
        float a = 0.f;
        for (int k = 0; k < 64; ++k) a += W1[t * 64 + k] * Wg0[k * 64 + c];
        M1[idx] = a;
    }
    for (int idx = tid; idx < 5 * 64; idx += blockDim.x) {
        int j = idx >> 6, c = idx & 63;
        float a = 0.f;
        for (int k = 0; k < 64; ++k) a += W2[j * 64 + k] * Wg0[(64 + k) * 64 + c];
        M2[idx] = a;
    }
    for (int c = tid; c < 64; c += blockDim.x) {
        float a = 0.f;
        for (int k = 0; k < 64; ++k)
            a += b1[k] * Wg0[k * 64 + c] + b2[k] * Wg0[(64 + k) * 64 + c];
        cvec[c] = a;
    }
}

// ---------- node features -> hb[i] = h0[i] * dinv[i] (bf16) ----------
__global__ void node_embed(const int* __restrict__ type_ids,
                           const float* __restrict__ f0, const float* __restrict__ f1,
                           const float* __restrict__ f2, const float* __restrict__ f3,
                           const float* __restrict__ f4,
                           const float* __restrict__ M1, const float* __restrict__ M2,
                           const float* __restrict__ cvec, const float* __restrict__ dinv,
                           unsigned short* __restrict__ hb, int n) {
    int i = blockIdx.x * (blockDim.x >> 6) + (threadIdx.x >> 6);
    int lane = threadIdx.x & 63;
    if (i >= n) return;
    int t = type_ids[i];
    float a = M1[t * 64 + lane] + cvec[lane];
    a += f0[i] * M2[0 * 64 + lane];
    a += f1[i] * M2[1 * 64 + lane];
    a += f2[i] * M2[2 * 64 + lane];
    a += f3[i] * M2[3 * 64 + lane];
    a += f4[i] * M2[4 * 64 + lane];
    hb[((unsigned)i << 6) | lane] = f2bf(a * dinv[i]);
}

// ---------- degree / CSR build ----------
__global__ void count_deg(const int* __restrict__ dst, int* __restrict__ deg, int e) {
    int i = blockIdx.x * blockDim.x + threadIdx.x;
    if (i < e) atomicAdd(&deg[dst[i]], 1);
}

// ---------- 3-phase scan (also emits dinv) ----------
#define SCAN_TILE 1024
__global__ void scan_local(const int* __restrict__ deg, int* __restrict__ loc,
                           int* __restrict__ tilesum, float* __restrict__ dinv, int n) {
    __shared__ int wsum[16];
    __shared__ int wexcl[16];
    const int tid = threadIdx.x;
    const int lane = tid & 63, w = tid >> 6;
    int i = blockIdx.x * SCAN_TILE + tid;
    int v = (i < n) ? deg[i] : 0;
    if (i < n) dinv[i] = rsqrtf((float)(v + 1));  // +1 self loop
    int incl = v;
#pragma unroll
    for (int ofs = 1; ofs < 64; ofs <<= 1) {
        int t = __shfl_up(incl, (unsigned)ofs, 64);
        if (lane >= ofs) incl += t;
    }
    if (lane == 63) wsum[w] = incl;
    __syncthreads();
    if (w == 0 && lane < 16) {
        int s = wsum[lane];
        int sc = s;
#pragma unroll
        for (int ofs = 1; ofs < 16; ofs <<= 1) {
            int t = __shfl_up(sc, (unsigned)ofs, 64);
            if (lane >= ofs) sc += t;
        }
        wexcl[lane] = sc - s;
        if (lane == 15) wsum[15] = sc;
    }
    __syncthreads();
    if (i < n) loc[i] = wexcl[w] + incl;
    if (tid == 0) tilesum[blockIdx.x] = wsum[15];
}

__global__ void scan_tiles(int* __restrict__ tilesum, int* __restrict__ tileoff, int nt) {
    int lane = threadIdx.x;
    int v = (lane < nt) ? tilesum[lane] : 0;
    int incl = v;
#pragma unroll
    for (int ofs = 1; ofs < 64; ofs <<= 1) {
        int t = __shfl_up(incl, (unsigned)ofs, 64);
        if (lane >= ofs) incl += t;
    }
    if (lane < nt) tileoff[lane] = incl - v;
}

__global__ void scan_add(const int* __restrict__ loc, const int* __restrict__ tileoff,
                         int* __restrict__ off, int* __restrict__ cursor, int n) {
    int i = blockIdx.x * blockDim.x + threadIdx.x;
    if (i >= n) return;
    int val = tileoff[i / SCAN_TILE] + loc[i];
    off[i + 1] = val;
    if (i + 1 < n) cursor[i + 1] = val;
    if (i == 0) { off[0] = 0; cursor[0] = 0; }
}

// ---------- fill CSR: ONE 2B nontemporal store per edge (src as ushort) ----------
__global__ void fill_csr(const int* __restrict__ src, const int* __restrict__ dst,
                         int* __restrict__ cursor, unsigned short* __restrict__ csr_u, int e) {
    int i = blockIdx.x * blockDim.x + threadIdx.x;
    if (i >= e) return;
    int s = src[i], d = dst[i];
    int pos = atomicAdd(&cursor[d], 1);
    __builtin_nontemporal_store((unsigned short)s, &csr_u[pos]);
}

// ---------- graph offsets from sorted batch ----------
__global__ void build_graph_off(const int* __restrict__ batch, int* __restrict__ go,
                                int n, int G) {
    int i = blockIdx.x * blockDim.x + threadIdx.x;
    if (i >= n) return;
    int b = batch[i];
    if (i == 0) {
        for (int g = 0; g <= b; ++g) go[g] = 0;
    } else {
        int p = batch[i - 1];
        if (p != b) for (int g = p + 1; g <= b; ++g) go[g] = i;
    }
    if (i == n - 1) {
        for (int g = b + 1; g <= G; ++g) go[g] = n;
    }
}

// ---------- conv gather core: 8 lanes/edge, uint4 rows, 4-deep batches ----------
// hb holds h*dinv(src) bf16; final *dinv[dst] applied after reduction.
// Row N of hb is zeros (mask target). csr_u front-padded (idx -1 ok) and
// tail-padded >=32 entries.
__device__ __forceinline__ void gather_add(float acc[8], uint4 v) {
    acc[0] += __uint_as_float(v.x << 16);
    acc[1] += __uint_as_float(v.x & 0xffff0000u);
    acc[2] += __uint_as_float(v.y << 16);
    acc[3] += __uint_as_float(v.y & 0xffff0000u);
    acc[4] += __uint_as_float(v.z << 16);
    acc[5] += __uint_as_float(v.z & 0xffff0000u);
    acc[6] += __uint_as_float(v.w << 16);
    acc[7] += __uint_as_float(v.w & 0xffff0000u);
}

__device__ __forceinline__ void node_aggregate(float acc[8],
                                               const unsigned short* __restrict__ hb,
                                               const unsigned short* __restrict__ csr_u,
                                               int i, int b, int deg, int N,
                                               int eg, int cc) {
#pragma unroll
    for (int q = 0; q < 8; ++q) acc[q] = 0.f;
    int nb = (deg + 8) >> 3;  // 8-slot batches covering deg+1 entries
#pragma unroll 1
    for (int t = 0; t < nb; t += 4) {
        int j0 = (t << 3) + eg;
        int j1 = j0 + 8, j2 = j0 + 16, j3 = j0 + 24;
        // 4 csr reads (unpredicated; padded) then 4 gathers in flight
        unsigned e0 = csr_u[b + j0 - 1];
        unsigned e1 = csr_u[b + j1 - 1];
        unsigned e2 = csr_u[b + j2 - 1];
        unsigned e3 = csr_u[b + j3 - 1];
        unsigned s0 = (j0 == 0) ? (unsigned)i : ((j0 <= deg) ? e0 : (unsigned)N);
        unsigned s1 = (j1 <= deg) ? e1 : (unsigned)N;
        unsigned s2 = (j2 <= deg) ? e2 : (unsigned)N;
        unsigned s3 = (j3 <= deg) ? e3 : (unsigned)N;
        uint4 v0 = *(const uint4*)&hb[(s0 << 6) + (cc << 3)];
        uint4 v1 = *(const uint4*)&hb[(s1 << 6) + (cc << 3)];
        uint4 v2 = *(const uint4*)&hb[(s2 << 6) + (cc << 3)];
        uint4 v3 = *(const uint4*)&hb[(s3 << 6) + (cc << 3)];
        gather_add(acc, v0);
        gather_add(acc, v1);
        gather_add(acc, v2);
        gather_add(acc, v3);
    }
#pragma unroll
    for (int q = 0; q < 8; ++q) {
        acc[q] += __shfl_xor(acc[q], 8, 64);
        acc[q] += __shfl_xor(acc[q], 16, 64);
        acc[q] += __shfl_xor(acc[q], 32, 64);
    }
}

__global__ void conv_gather(const unsigned short* __restrict__ hb,
                            const int* __restrict__ off, const unsigned short* __restrict__ csr_u,
                            const float* __restrict__ dinv,
                            const float* __restrict__ bias, float* __restrict__ out,
                            int n) {
    int i = blockIdx.x * (blockDim.x >> 6) + (threadIdx.x >> 6);
    if (i >= n) return;
    const int lane = threadIdx.x & 63;
    const int eg = lane >> 3, cc = lane & 7;
    int b = off[i], e = off[i + 1];
    float di = dinv[i];
    float acc[8];
    node_aggregate(acc, hb, csr_u, i, b, e - b, n, eg, cc);
    if (eg == 0) {
        const float4* b4 = (const float4*)bias;
        float4 bb0 = b4[cc * 2], bb1 = b4[cc * 2 + 1];
        float4 o0 = make_float4(acc[0] * di + bb0.x, acc[1] * di + bb0.y,
                                acc[2] * di + bb0.z, acc[3] * di + bb0.w);
        float4 o1 = make_float4(acc[4] * di + bb1.x, acc[5] * di + bb1.y,
                                acc[6] * di + bb1.z, acc[7] * di + bb1.w);
        float4* o = (float4*)&out[((size_t)i << 6) + (cc << 3)];
        o[0] = o0;
        o[1] = o1;
    }
}

// ---------- conv + relu + mean-pool (layer 2): one wave per (graph, slice) ----------
#define POOL_SLICES 16
__global__ void conv_relu_pool(const unsigned short* __restrict__ hb,
                               const int* __restrict__ off, const unsigned short* __restrict__ csr_u,
                               const float* __restrict__ dinv,
                               const float* __restrict__ bias, const int* __restrict__ go,
                               float* __restrict__ pooled, int* __restrict__ cnt,
                               int n, int G) {
    int wave = blockIdx.x * (blockDim.x >> 6) + (threadIdx.x >> 6);
    int g = wave >> 4, k = wave & (POOL_SLICES - 1);
    if (g >= G) return;
    const int lane = threadIdx.x & 63;
    const int eg = lane >> 3, cc = lane & 7;
    int gs = go[g], ge = go[g + 1];
    int cntg = ge - gs;
    if (k == 0 && lane == 0) cnt[g] = cntg;   // plain store, deterministic
    if (cntg == 0) return;
    int per = (cntg + POOL_SLICES - 1) >> 4;
    int s0 = gs + k * per;
    int s1 = min(ge, s0 + per);
    if (s0 >= s1) return;
    const float4* b4 = (const float4*)bias;
    float4 bb0 = b4[cc * 2], bb1 = b4[cc * 2 + 1];
    float bl[8] = {bb0.x, bb0.y, bb0.z, bb0.w, bb1.x, bb1.y, bb1.z, bb1.w};
    float accp[8];
#pragma unroll
    for (int q = 0; q < 8; ++q) accp[q] = 0.f;
    for (int i = s0; i < s1; ++i) {
        int b = off[i], e = off[i + 1];
        float di = dinv[i];
        float acc[8];
        node_aggregate(acc, hb, csr_u, i, b, e - b, n, eg, cc);
#pragma unroll
        for (int q = 0; q < 8; ++q) accp[q] += fmaxf(acc[q] * di + bl[q], 0.f);
    }
    atomicAdd(&pooled[g * 64 + (cc << 3) + eg], accp[eg]);
}

// ---------- batchnorm stats: per-block partials ----------
__global__ void bn_stats(const float* __restrict__ y, float* __restrict__ partials, int n) {
    __shared__ float sh[4][128];
    int lane = threadIdx.x & 63;
    int w = threadIdx.x >> 6;
    int waves_per_blk = blockDim.x >> 6;
    float s = 0.f, ss = 0.f;
    for (int i = blockIdx.x * waves_per_blk + w; i < n; i += gridDim.x * waves_per_blk) {
        float v = y[((size_t)i << 6) | lane];
        s += v;
        ss += v * v;
    }
    sh[w][lane] = s;
    sh[w][64 + lane] = ss;
    __syncthreads();
    if (threadIdx.x < 128) {
        float a = sh[0][threadIdx.x] + sh[1][threadIdx.x] + sh[2][threadIdx.x] + sh[3][threadIdx.x];
        partials[blockIdx.x * 128 + threadIdx.x] = a;
    }
}

// parallel finalize: 1024 threads, 8 slices per channel, LDS tree
__global__ __launch_bounds__(1024) void bn_finalize(const float* __restrict__ partials, int nblk,
                            const float* __restrict__ gamma, const float* __restrict__ beta,
                            float* __restrict__ scsh, int n) {
    __shared__ float red[8][128];
    __shared__ float tot[128];
    int t = threadIdx.x;
    int ch = t & 127, sl = t >> 7;
    float a = 0.f;
#pragma unroll 8
    for (int b = sl; b < nblk; b += 8) a += partials[b * 128 + ch];
    red[sl][ch] = a;
    __syncthreads();
    if (t < 128) {
        float s = 0.f;
#pragma unroll
        for (int i = 0; i < 8; ++i) s += red[i][t];
        tot[t] = s;
    }
    __syncthreads();
    if (t < 64) {
        float mean = tot[t] / (float)n;
        float var = tot[64 + t] / (float)n - mean * mean;
        float sc = rsqrtf(var + 1e-5f) * gamma[t];
        scsh[t] = sc;
        scsh[64 + t] = beta[t] - mean * sc;
    }
}

// ---------- tiled bn+relu+GEMM: hb = (relu(y*sc+sh) @ W) * dinv[row], bf16 ----------
// 256 threads, 128-node tile, 4x8 outputs per lane. kc loop NOT unrolled
// (R7: full unroll -> live-range explosion -> spills).
struct alignas(16) us8 { unsigned short v[8]; };
__global__ __launch_bounds__(256, 2) void bn_relu_gemm(const float* __restrict__ y,
                             const float* __restrict__ scsh, const float* __restrict__ W,
                             const float* __restrict__ dinv,
                             unsigned short* __restrict__ hb, int n) {
    __shared__ float4 yt4[128 * 16];
    __shared__ float4 wt4[64 * 16];
    float* wt = (float*)wt4;
    const int t = threadIdx.x;          // 256 threads
    const int base = blockIdx.x * 128;

    // stage W^T: read W[k][c0..c0+3] coalesced, scatter-transpose into wt[c][k]
    const float4* W4 = (const float4*)W;
#pragma unroll
    for (int i = 0; i < 4; ++i) {
        int g = t + 256 * i;
        int k = g >> 4;                 // W row = input channel
        int c0 = (g & 15) << 2;         // output-channel group
        float4 wv = W4[g];
        float wvf[4] = {wv.x, wv.y, wv.z, wv.w};
#pragma unroll
        for (int j = 0; j < 4; ++j) {
            int c = c0 + j;
            wt[c * 64 + (((k >> 2) ^ ((c >> 2) & 15)) << 2) + (k & 3)] = wvf[j];
        }
    }
    // stage yt = relu(y*sc+sh) (128x64 = 2048 float4)
    const float4* y4 = (const float4*)y;
#pragma unroll
    for (int i = 0; i < 8; ++i) {
        int g = t + 256 * i;
        int r = g >> 4, kc = g & 15;
        int row = base + r;
        float4 v = make_float4(0.f, 0.f, 0.f, 0.f);
        if (row < n) v = y4[(size_t)row * 16 + kc];
        int c0 = kc << 2;
        v.x = fmaxf(v.x * scsh[c0 + 0] + scsh[64 + c0 + 0], 0.f);
        v.y = fmaxf(v.y * scsh[c0 + 1] + scsh[64 + c0 + 1], 0.f);
        v.z = fmaxf(v.z * scsh[c0 + 2] + scsh[64 + c0 + 2], 0.f);
        v.w = fmaxf(v.w * scsh[c0 + 3] + scsh[64 + c0 + 3], 0.f);
        yt4[r * 16 + (kc ^ ((r >> 2) & 15))] = v;
    }
    __syncthreads();

    const int w = t >> 6;              // wave 0..3 -> nodes [w*32, w*32+32)
    const int lane = t & 63;
    const int ng = lane >> 3;          // 0..7
    const int cg = lane & 7;           // 0..7
    const int rl = w * 32 + ng * 4;    // local rows rl..rl+3
    const int c0 = cg * 8;             // channels c0..c0+7
    const int sa = (rl >> 2) & 15;     // same for all 4 rows
    float acc[4][8];
#pragma unroll
    for (int m = 0; m < 4; ++m)
#pragma unroll
        for (int j = 0; j < 8; ++j) acc[m][j] = 0.f;

#pragma unroll 1
    for (int kc = 0; kc < 16; ++kc) {
        float4 a[4];
#pragma unroll
        for (int m = 0; m < 4; ++m) a[m] = yt4[(rl + m) * 16 + (kc ^ sa)];
#pragma unroll
        for (int j = 0; j < 8; ++j) {
            int c = c0 + j;
            float4 b = wt4[c * 16 + (kc ^ ((c >> 2) & 15))];
#pragma unroll
            for (int m = 0; m < 4; ++m)
                acc[m][j] += a[m].x * b.x + a[m].y * b.y +
                             a[m].z * b.z + a[m].w * b.w;
        }
    }

#pragma unroll
    for (int m = 0; m < 4; ++m) {
        int row = base + rl + m;
        if (row < n) {
            float dv = dinv[row];
            us8 p;
#pragma unroll
            for (int j = 0; j < 8; ++j) p.v[j] = f2bf(acc[m][j] * dv);
            *(us8*)&hb[((size_t)row << 6) | c0] = p;
        }
    }
}

// ---------- final: out[g] = (pooled[g]/cnt) @ Wout + bout ----------
__global__ void final_out(const float* __restrict__ pooled, const int* __restrict__ cnt,
                          const float* __restrict__ Wout, const float* __restrict__ bout,
                          float* __restrict__ out, int G) {
    int idx = blockIdx.x * blockDim.x + threadIdx.x;
    if (idx >= G * 4) return;
    int g = idx >> 2, o = idx & 3;
    float inv = 1.f / fmaxf((float)cnt[g], 1.f);
    float a = 0.f;
    for (int k = 0; k < 64; ++k) a += pooled[g * 64 + k] * Wout[k * 4 + o];
    out[idx] = a * inv + bout[o];
}

extern "C" void kernel_launch(void* const* d_in, const int* in_sizes, int n_in,
                              void* d_out, int out_size, void* d_ws, size_t ws_size,
                              hipStream_t stream) {
    const int N = in_sizes[0];
    const int E = in_sizes[6] / 2;
    const int T = in_sizes[8] / 64;
    const int G = out_size / 4;

    const int*   type_ids = (const int*)d_in[0];
    const float* fc   = (const float*)d_in[1];
    const float* fgm  = (const float*)d_in[2];
    const float* fpos = (const float*)d_in[3];
    const float* fr   = (const float*)d_in[4];
    const float* fvid = (const float*)d_in[5];
    const int*   ei   = (const int*)d_in[6];
    const int*   batch = (const int*)d_in[7];
    const float* W1 = (const float*)d_in[8];
    const float* b1 = (const float*)d_in[9];
    const float* W2 = (const float*)d_in[10];
    const float* b2 = (const float*)d_in[11];
    const float* Wg0 = (const float*)d_in[12];
    const float* bg0 = (const float*)d_in[13];
    const float* Wg1 = (const float*)d_in[14];
    const float* bg1 = (const float*)d_in[15];
    const float* Wg2 = (const float*)d_in[16];
    const float* bg2 = (const float*)d_in[17];
    const float* gam0 = (const float*)d_in[18];
    const float* bet0 = (const float*)d_in[19];
    const float* gam1 = (const float*)d_in[20];
    const float* bet1 = (const float*)d_in[21];
    const float* Wout = (const float*)d_in[22];
    const float* bout = (const float*)d_in[23];

    const int* e_src = ei;
    const int* e_dst = ei + E;

    // ---- workspace layout ----
    char* ws = (char*)d_ws;
    size_t o = 0;
    auto alloc = [&](size_t bytes) -> char* {
        char* p = ws + o;
        o += (bytes + 255) & ~(size_t)255;
        return p;
    };
    const int NBLK_BN = 256;
    const int NTILES = (N + SCAN_TILE - 1) / SCAN_TILE;
    unsigned short* hb = (unsigned short*)alloc((size_t)(N + 1) * 64 * 2); // +1 zero row
    float* y        = (float*)alloc((size_t)N * 64 * 4);
    int*   deg      = (int*)alloc((size_t)N * 4);
    float* dinv     = (float*)alloc((size_t)N * 4);
    int*   off      = (int*)alloc((size_t)(N + 1) * 4);
    int*   cursor   = (int*)alloc((size_t)N * 4);
    int*   loc      = (int*)alloc((size_t)N * 4);
    int*   tilesum  = (int*)alloc((size_t)NTILES * 4);
    int*   tileoff  = (int*)alloc((size_t)NTILES * 4);
    unsigned short* csrBuf = (unsigned short*)alloc(((size_t)E + 48) * 2);
    unsigned short* csr_u  = csrBuf + 1;   // front pad: csr_u[-1] valid
    int*   go       = (int*)alloc((size_t)(G + 1) * 4);
    float* part0    = (float*)alloc((size_t)NBLK_BN * 128 * 4);
    float* part1    = (float*)alloc((size_t)NBLK_BN * 128 * 4);
    float* scsh0    = (float*)alloc(128 * 4);
    float* scsh1    = (float*)alloc(128 * 4);
    float* pooled   = (float*)alloc((size_t)G * 64 * 4);
    int*   cnt      = (int*)alloc((size_t)G * 4);
    float* M1       = (float*)alloc((size_t)T * 64 * 4);
    float* M2       = (float*)alloc(5 * 64 * 4);
    float* cvec     = (float*)alloc(64 * 4);
    (void)ws_size;

    hipMemsetAsync(deg, 0, (size_t)N * 4, stream);
    hipMemsetAsync(csrBuf, 0, 2, stream);             // front pad entry
    hipMemsetAsync(csr_u + E, 0, 40 * 2, stream);     // tail pad (40 entries)
    hipMemsetAsync(hb + (size_t)N * 64, 0, 128, stream);  // zero row N (mask target)
    hipMemsetAsync(pooled, 0, (size_t)G * 64 * 4, stream);

    const int waves_per_blk = 4;                   // 256 threads
    const int nblk_nodes = (N + waves_per_blk - 1) / waves_per_blk;
    const int nblk_gemm = (N + 127) / 128;

    // graph structure (dinv needed by node_embed)
    count_deg<<<(E + 255) / 256, 256, 0, stream>>>(e_dst, deg, E);
    scan_local<<<NTILES, SCAN_TILE, 0, stream>>>(deg, loc, tilesum, dinv, N);
    scan_tiles<<<1, 64, 0, stream>>>(tilesum, tileoff, NTILES);
    scan_add<<<(N + 255) / 256, 256, 0, stream>>>(loc, tileoff, off, cursor, N);
    fill_csr<<<(E + 255) / 256, 256, 0, stream>>>(e_src, e_dst, cursor, csr_u, E);
    build_graph_off<<<(N + 255) / 256, 256, 0, stream>>>(batch, go, N, G);

    precompute_mats<<<1, 256, 0, stream>>>(W1, b1, W2, b2, Wg0, M1, M2, cvec, T);
    node_embed<<<nblk_nodes, 256, 0, stream>>>(type_ids, fc, fgm, fpos, fr, fvid,
                                               M1, M2, cvec, dinv, hb, N);

    // layer 0
    conv_gather<<<nblk_nodes, 256, 0, stream>>>(hb, off, csr_u, dinv, bg0, y, N);
    bn_stats<<<NBLK_BN, 256, 0, stream>>>(y, part0, N);
    bn_finalize<<<1, 1024, 0, stream>>>(part0, NBLK_BN, gam0, bet0, scsh0, N);
    bn_relu_gemm<<<nblk_gemm, 256, 0, stream>>>(y, scsh0, Wg1, dinv, hb, N);

    // layer 1
    conv_gather<<<nblk_nodes, 256, 0, stream>>>(hb, off, csr_u, dinv, bg1, y, N);
    bn_stats<<<NBLK_BN, 256, 0, stream>>>(y, part1, N);
    bn_finalize<<<1, 1024, 0, stream>>>(part1, NBLK_BN, gam1, bet1, scsh1, N);
    bn_relu_gemm<<<nblk_gemm, 256, 0, stream>>>(y, scsh1, Wg2, dinv, hb, N);

    // layer 2: conv + relu + graph-sliced mean-pool
    {
        int waves = G * POOL_SLICES;
        int blocks = (waves + waves_per_blk - 1) / waves_per_blk;
        conv_relu_pool<<<blocks, 256, 0, stream>>>(hb, off, csr_u, dinv, bg2, go,
                                                   pooled, cnt, N, G);
    }

    final_out<<<(G * 4 + 255) / 256, 256, 0, stream>>>(pooled, cnt, Wout, bout, (float*)d_out, G);
}

// Round 15
// 291.721 us; speedup vs baseline: 1.0115x; 1.0115x over previous
//
#include <hip/hip_runtime.h>
#include <hip/hip_bf16.h>

// GCN: embed -> (conv -> bn -> relu) x2 -> conv(+relu+pool fused) -> linear
// H = 64.
// R14: CSR build via two-pass bucketing. R12/R13 counters proved random 2-4B
//      scatters pay a full line writeback per STORE (cross-XCD L2 bounce,
//      ~66B/store, invariant to entry size; nontemporal made it worse).
//      Pass A: workgroup counting-sort into 64 dst-range buckets (LDS hist,
//      contiguous claimed slices -> dense full-line writes).
//      Pass B: 4 co-resident blocks per bucket scatter into its ~32KB CSR
//      region -> line writers localized. Conv structure unchanged from R13.

// bf16 helpers
__device__ __forceinline__ unsigned short f2bf(float f) {
    unsigned int x = (unsigned int)__float_as_int(f);
    x += 0x7fffu + ((x >> 16) & 1u);
    return (unsigned short)(x >> 16);
}

// ---------- tiny precompute: fold one-hot/numeric linears through Wg0 ----------
__global__ void precompute_mats(const float* __restrict__ W1, const float* __restrict__ b1,
                                const float* __restrict__ W2, const float* __restrict__ b2,
                                const float* __restrict__ Wg0,
                                float* __restrict__ M1, float* __restrict__ M2,
                                float* __restrict__ cvec, int T) {
    int tid = threadIdx.x;
    for (int idx = tid; idx < T * 64; idx += blockDim.x) {
        int t = idx >> 6, c = idx & 63;
        float a = 0.f;
        for (int k = 0; k < 64; ++k) a += W1[t * 64 + k] * Wg0[k * 64 + c];
        M1[idx] = a;
    }
    for (int idx = tid; idx < 5 * 64; idx += blockDim.x) {
        int j = idx >> 6, c = idx & 63;
        float a = 0.f;
        for (int k = 0; k < 64; ++k) a += W2[j * 64 + k] * Wg0[(64 + k) * 64 + c];
        M2[idx] = a;
    }
    for (int c = tid; c < 64; c += blockDim.x) {
        float a = 0.f;
        for (int k = 0; k < 64; ++k)
            a += b1[k] * Wg0[k * 64 + c] + b2[k] * Wg0[(64 + k) * 64 + c];
        cvec[c] = a;
    }
}

// ---------- node features -> hb[i] = h0[i] * dinv[i] (bf16) ----------
__global__ void node_embed(const int* __restrict__ type_ids,
                           const float* __restrict__ f0, const float* __restrict__ f1,
                           const float* __restrict__ f2, const float* __restrict__ f3,
                           const float* __restrict__ f4,
                           const float* __restrict__ M1, const float* __restrict__ M2,
                           const float* __restrict__ cvec, const float* __restrict__ dinv,
                           unsigned short* __restrict__ hb, int n) {
    int i = blockIdx.x * (blockDim.x >> 6) + (threadIdx.x >> 6);
    int lane = threadIdx.x & 63;
    if (i >= n) return;
    int t = type_ids[i];
    float a = M1[t * 64 + lane] + cvec[lane];
    a += f0[i] * M2[0 * 64 + lane];
    a += f1[i] * M2[1 * 64 + lane];
    a += f2[i] * M2[2 * 64 + lane];
    a += f3[i] * M2[3 * 64 + lane];
    a += f4[i] * M2[4 * 64 + lane];
    hb[((unsigned)i << 6) | lane] = f2bf(a * dinv[i]);
}

// ---------- degree / CSR build ----------
__global__ void count_deg(const int* __restrict__ dst, int* __restrict__ deg, int e) {
    int i = blockIdx.x * blockDim.x + threadIdx.x;
    if (i < e) atomicAdd(&deg[dst[i]], 1);
}

// ---------- 3-phase scan (also emits dinv) ----------
#define SCAN_TILE 1024
__global__ void scan_local(const int* __restrict__ deg, int* __restrict__ loc,
                           int* __restrict__ tilesum, float* __restrict__ dinv, int n) {
    __shared__ int wsum[16];
    __shared__ int wexcl[16];
    const int tid = threadIdx.x;
    const int lane = tid & 63, w = tid >> 6;
    int i = blockIdx.x * SCAN_TILE + tid;
    int v = (i < n) ? deg[i] : 0;
    if (i < n) dinv[i] = rsqrtf((float)(v + 1));  // +1 self loop
    int incl = v;
#pragma unroll
    for (int ofs = 1; ofs < 64; ofs <<= 1) {
        int t = __shfl_up(incl, (unsigned)ofs, 64);
        if (lane >= ofs) incl += t;
    }
    if (lane == 63) wsum[w] = incl;
    __syncthreads();
    if (w == 0 && lane < 16) {
        int s = wsum[lane];
        int sc = s;
#pragma unroll
        for (int ofs = 1; ofs < 16; ofs <<= 1) {
            int t = __shfl_up(sc, (unsigned)ofs, 64);
            if (lane >= ofs) sc += t;
        }
        wexcl[lane] = sc - s;
        if (lane == 15) wsum[15] = sc;
    }
    __syncthreads();
    if (i < n) loc[i] = wexcl[w] + incl;
    if (tid == 0) tilesum[blockIdx.x] = wsum[15];
}

__global__ void scan_tiles(int* __restrict__ tilesum, int* __restrict__ tileoff, int nt) {
    int lane = threadIdx.x;
    int v = (lane < nt) ? tilesum[lane] : 0;
    int incl = v;
#pragma unroll
    for (int ofs = 1; ofs < 64; ofs <<= 1) {
        int t = __shfl_up(incl, (unsigned)ofs, 64);
        if (lane >= ofs) incl += t;
    }
    if (lane < nt) tileoff[lane] = incl - v;
}

__global__ void scan_add(const int* __restrict__ loc, const int* __restrict__ tileoff,
                         int* __restrict__ off, int* __restrict__ cursor, int n) {
    int i = blockIdx.x * blockDim.x + threadIdx.x;
    if (i >= n) return;
    int val = tileoff[i / SCAN_TILE] + loc[i];
    off[i + 1] = val;
    if (i + 1 < n) cursor[i + 1] = val;
    if (i == 0) { off[0] = 0; cursor[0] = 0; }
}

// ---------- CSR build pass 0: bucket cursors from off ----------
#define NB 64          // dst-range buckets, bucket = dst >> 10
__global__ void init_buckets(const int* __restrict__ off, int* __restrict__ bkt_cursor,
                             int N) {
    int b = threadIdx.x;
    if (b < NB) bkt_cursor[b] = off[min(b << 10, N)];
}

// ---------- CSR build pass A: counting-sort edges into dst-range buckets ----------
#define EPB 8192       // edges per block
__global__ void bucket_edges(const int* __restrict__ src, const int* __restrict__ dst,
                             int* __restrict__ bkt_cursor, unsigned* __restrict__ bucketed,
                             int E) {
    __shared__ int hist[NB];
    __shared__ int base_[NB];
    const int t = threadIdx.x;
    int start = blockIdx.x * EPB;
    int end = min(E, start + EPB);
    if (t < NB) hist[t] = 0;
    __syncthreads();
    for (int i = start + t; i < end; i += 256) {
        int b = dst[i] >> 10;
        atomicAdd(&hist[b], 1);
    }
    __syncthreads();
    if (t < NB) {
        base_[t] = atomicAdd(&bkt_cursor[t], hist[t]);
        hist[t] = 0;
    }
    __syncthreads();
    for (int i = start + t; i < end; i += 256) {
        int d = dst[i];
        int b = d >> 10;
        int slot = atomicAdd(&hist[b], 1);
        bucketed[base_[b] + slot] = ((unsigned)src[i] << 16) | (unsigned)d;
    }
}

// ---------- CSR build pass B: per-bucket scatter (writers localized) ----------
#define SCAT_SLICES 4
__global__ void scatter_csr(const unsigned* __restrict__ bucketed, const int* __restrict__ off,
                            int* __restrict__ cursor, unsigned short* __restrict__ csr_u,
                            int N) {
    int wg = blockIdx.x;
    int b = wg / SCAT_SLICES, q = wg % SCAT_SLICES;
    int bstart = off[min(b << 10, N)];
    int bend = off[min((b + 1) << 10, N)];
    int cntb = bend - bstart;
    if (cntb == 0) return;
    int per = (cntb + SCAT_SLICES - 1) / SCAT_SLICES;
    int s0 = bstart + q * per;
    int s1 = min(bend, s0 + per);
    for (int i = s0 + (int)threadIdx.x; i < s1; i += 256) {
        unsigned u = bucketed[i];
        int s = (int)(u >> 16);
        int d = (int)(u & 0xffffu);
        int pos = atomicAdd(&cursor[d], 1);
        csr_u[pos] = (unsigned short)s;
    }
}

// ---------- graph offsets from sorted batch ----------
__global__ void build_graph_off(const int* __restrict__ batch, int* __restrict__ go,
                                int n, int G) {
    int i = blockIdx.x * blockDim.x + threadIdx.x;
    if (i >= n) return;
    int b = batch[i];
    if (i == 0) {
        for (int g = 0; g <= b; ++g) go[g] = 0;
    } else {
        int p = batch[i - 1];
        if (p != b) for (int g = p + 1; g <= b; ++g) go[g] = i;
    }
    if (i == n - 1) {
        for (int g = b + 1; g <= G; ++g) go[g] = n;
    }
}

// ---------- conv gather core: 8 lanes/edge, uint4 rows, 4-deep batches ----------
// hb holds h*dinv(src) bf16; final *dinv[dst] applied after reduction.
// Row N of hb is zeros (mask target). csr_u front-padded (idx -1 ok) and
// tail-padded >=32 entries.
__device__ __forceinline__ void gather_add(float acc[8], uint4 v) {
    acc[0] += __uint_as_float(v.x << 16);
    acc[1] += __uint_as_float(v.x & 0xffff0000u);
    acc[2] += __uint_as_float(v.y << 16);
    acc[3] += __uint_as_float(v.y & 0xffff0000u);
    acc[4] += __uint_as_float(v.z << 16);
    acc[5] += __uint_as_float(v.z & 0xffff0000u);
    acc[6] += __uint_as_float(v.w << 16);
    acc[7] += __uint_as_float(v.w & 0xffff0000u);
}

__device__ __forceinline__ void node_aggregate(float acc[8],
                                               const unsigned short* __restrict__ hb,
                                               const unsigned short* __restrict__ csr_u,
                                               int i, int b, int deg, int N,
                                               int eg, int cc) {
#pragma unroll
    for (int q = 0; q < 8; ++q) acc[q] = 0.f;
    int nb = (deg + 8) >> 3;  // 8-slot batches covering deg+1 entries
#pragma unroll 1
    for (int t = 0; t < nb; t += 4) {
        int j0 = (t << 3) + eg;
        int j1 = j0 + 8, j2 = j0 + 16, j3 = j0 + 24;
        unsigned e0 = csr_u[b + j0 - 1];
        unsigned e1 = csr_u[b + j1 - 1];
        unsigned e2 = csr_u[b + j2 - 1];
        unsigned e3 = csr_u[b + j3 - 1];
        unsigned s0 = (j0 == 0) ? (unsigned)i : ((j0 <= deg) ? e0 : (unsigned)N);
        unsigned s1 = (j1 <= deg) ? e1 : (unsigned)N;
        unsigned s2 = (j2 <= deg) ? e2 : (unsigned)N;
        unsigned s3 = (j3 <= deg) ? e3 : (unsigned)N;
        uint4 v0 = *(const uint4*)&hb[(s0 << 6) + (cc << 3)];
        uint4 v1 = *(const uint4*)&hb[(s1 << 6) + (cc << 3)];
        uint4 v2 = *(const uint4*)&hb[(s2 << 6) + (cc << 3)];
        uint4 v3 = *(const uint4*)&hb[(s3 << 6) + (cc << 3)];
        gather_add(acc, v0);
        gather_add(acc, v1);
        gather_add(acc, v2);
        gather_add(acc, v3);
    }
#pragma unroll
    for (int q = 0; q < 8; ++q) {
        acc[q] += __shfl_xor(acc[q], 8, 64);
        acc[q] += __shfl_xor(acc[q], 16, 64);
        acc[q] += __shfl_xor(acc[q], 32, 64);
    }
}

__global__ void conv_gather(const unsigned short* __restrict__ hb,
                            const int* __restrict__ off, const unsigned short* __restrict__ csr_u,
                            const float* __restrict__ dinv,
                            const float* __restrict__ bias, float* __restrict__ out,
                            int n) {
    int i = blockIdx.x * (blockDim.x >> 6) + (threadIdx.x >> 6);
    if (i >= n) return;
    const int lane = threadIdx.x & 63;
    const int eg = lane >> 3, cc = lane & 7;
    int b = off[i], e = off[i + 1];
    float di = dinv[i];
    float acc[8];
    node_aggregate(acc, hb, csr_u, i, b, e - b, n, eg, cc);
    if (eg == 0) {
        const float4* b4 = (const float4*)bias;
        float4 bb0 = b4[cc * 2], bb1 = b4[cc * 2 + 1];
        float4 o0 = make_float4(acc[0] * di + bb0.x, acc[1] * di + bb0.y,
                                acc[2] * di + bb0.z, acc[3] * di + bb0.w);
        float4 o1 = make_float4(acc[4] * di + bb1.x, acc[5] * di + bb1.y,
                                acc[6] * di + bb1.z, acc[7] * di + bb1.w);
        float4* o = (float4*)&out[((size_t)i << 6) + (cc << 3)];
        o[0] = o0;
        o[1] = o1;
    }
}

// ---------- conv + relu + mean-pool (layer 2): one wave per (graph, slice) ----------
#define POOL_SLICES 16
__global__ void conv_relu_pool(const unsigned short* __restrict__ hb,
                               const int* __restrict__ off, const unsigned short* __restrict__ csr_u,
                               const float* __restrict__ dinv,
                               const float* __restrict__ bias, const int* __restrict__ go,
                               float* __restrict__ pooled, int* __restrict__ cnt,
                               int n, int G) {
    int wave = blockIdx.x * (blockDim.x >> 6) + (threadIdx.x >> 6);
    int g = wave >> 4, k = wave & (POOL_SLICES - 1);
    if (g >= G) return;
    const int lane = threadIdx.x & 63;
    const int eg = lane >> 3, cc = lane & 7;
    int gs = go[g], ge = go[g + 1];
    int cntg = ge - gs;
    if (k == 0 && lane == 0) cnt[g] = cntg;   // plain store, deterministic
    if (cntg == 0) return;
    int per = (cntg + POOL_SLICES - 1) >> 4;
    int s0 = gs + k * per;
    int s1 = min(ge, s0 + per);
    if (s0 >= s1) return;
    const float4* b4 = (const float4*)bias;
    float4 bb0 = b4[cc * 2], bb1 = b4[cc * 2 + 1];
    float bl[8] = {bb0.x, bb0.y, bb0.z, bb0.w, bb1.x, bb1.y, bb1.z, bb1.w};
    float accp[8];
#pragma unroll
    for (int q = 0; q < 8; ++q) accp[q] = 0.f;
    for (int i = s0; i < s1; ++i) {
        int b = off[i], e = off[i + 1];
        float di = dinv[i];
        float acc[8];
        node_aggregate(acc, hb, csr_u, i, b, e - b, n, eg, cc);
#pragma unroll
        for (int q = 0; q < 8; ++q) accp[q] += fmaxf(acc[q] * di + bl[q], 0.f);
    }
    atomicAdd(&pooled[g * 64 + (cc << 3) + eg], accp[eg]);
}

// ---------- batchnorm stats: per-block partials ----------
__global__ void bn_stats(const float* __restrict__ y, float* __restrict__ partials, int n) {
    __shared__ float sh[4][128];
    int lane = threadIdx.x & 63;
    int w = threadIdx.x >> 6;
    int waves_per_blk = blockDim.x >> 6;
    float s = 0.f, ss = 0.f;
    for (int i = blockIdx.x * waves_per_blk + w; i < n; i += gridDim.x * waves_per_blk) {
        float v = y[((size_t)i << 6) | lane];
        s += v;
        ss += v * v;
    }
    sh[w][lane] = s;
    sh[w][64 + lane] = ss;
    __syncthreads();
    if (threadIdx.x < 128) {
        float a = sh[0][threadIdx.x] + sh[1][threadIdx.x] + sh[2][threadIdx.x] + sh[3][threadIdx.x];
        partials[blockIdx.x * 128 + threadIdx.x] = a;
    }
}

// parallel finalize: 1024 threads, 8 slices per channel, LDS tree
__global__ __launch_bounds__(1024) void bn_finalize(const float* __restrict__ partials, int nblk,
                            const float* __restrict__ gamma, const float* __restrict__ beta,
                            float* __restrict__ scsh, int n) {
    __shared__ float red[8][128];
    __shared__ float tot[128];
    int t = threadIdx.x;
    int ch = t & 127, sl = t >> 7;
    float a = 0.f;
#pragma unroll 8
    for (int b = sl; b < nblk; b += 8) a += partials[b * 128 + ch];
    red[sl][ch] = a;
    __syncthreads();
    if (t < 128) {
        float s = 0.f;
#pragma unroll
        for (int i = 0; i < 8; ++i) s += red[i][t];
        tot[t] = s;
    }
    __syncthreads();
    if (t < 64) {
        float mean = tot[t] / (float)n;
        float var = tot[64 + t] / (float)n - mean * mean;
        float sc = rsqrtf(var + 1e-5f) * gamma[t];
        scsh[t] = sc;
        scsh[64 + t] = beta[t] - mean * sc;
    }
}

// ---------- tiled bn+relu+GEMM: hb = (relu(y*sc+sh) @ W) * dinv[row], bf16 ----------
// 256 threads, 128-node tile, 4x8 outputs per lane. kc loop NOT unrolled
// (R7: full unroll -> live-range explosion -> spills).
struct alignas(16) us8 { unsigned short v[8]; };
__global__ __launch_bounds__(256, 2) void bn_relu_gemm(const float* __restrict__ y,
                             const float* __restrict__ scsh, const float* __restrict__ W,
                             const float* __restrict__ dinv,
                             unsigned short* __restrict__ hb, int n) {
    __shared__ float4 yt4[128 * 16];
    __shared__ float4 wt4[64 * 16];
    float* wt = (float*)wt4;
    const int t = threadIdx.x;          // 256 threads
    const int base = blockIdx.x * 128;

    // stage W^T: read W[k][c0..c0+3] coalesced, scatter-transpose into wt[c][k]
    const float4* W4 = (const float4*)W;
#pragma unroll
    for (int i = 0; i < 4; ++i) {
        int g = t + 256 * i;
        int k = g >> 4;                 // W row = input channel
        int c0 = (g & 15) << 2;         // output-channel group
        float4 wv = W4[g];
        float wvf[4] = {wv.x, wv.y, wv.z, wv.w};
#pragma unroll
        for (int j = 0; j < 4; ++j) {
            int c = c0 + j;
            wt[c * 64 + (((k >> 2) ^ ((c >> 2) & 15)) << 2) + (k & 3)] = wvf[j];
        }
    }
    // stage yt = relu(y*sc+sh) (128x64 = 2048 float4)
    const float4* y4 = (const float4*)y;
#pragma unroll
    for (int i = 0; i < 8; ++i) {
        int g = t + 256 * i;
        int r = g >> 4, kc = g & 15;
        int row = base + r;
        float4 v = make_float4(0.f, 0.f, 0.f, 0.f);
        if (row < n) v = y4[(size_t)row * 16 + kc];
        int c0 = kc << 2;
        v.x = fmaxf(v.x * scsh[c0 + 0] + scsh[64 + c0 + 0], 0.f);
        v.y = fmaxf(v.y * scsh[c0 + 1] + scsh[64 + c0 + 1], 0.f);
        v.z = fmaxf(v.z * scsh[c0 + 2] + scsh[64 + c0 + 2], 0.f);
        v.w = fmaxf(v.w * scsh[c0 + 3] + scsh[64 + c0 + 3], 0.f);
        yt4[r * 16 + (kc ^ ((r >> 2) & 15))] = v;
    }
    __syncthreads();

    const int w = t >> 6;              // wave 0..3 -> nodes [w*32, w*32+32)
    const int lane = t & 63;
    const int ng = lane >> 3;          // 0..7
    const int cg = lane & 7;           // 0..7
    const int rl = w * 32 + ng * 4;    // local rows rl..rl+3
    const int c0 = cg * 8;             // channels c0..c0+7
    const int sa = (rl >> 2) & 15;     // same for all 4 rows
    float acc[4][8];
#pragma unroll
    for (int m = 0; m < 4; ++m)
#pragma unroll
        for (int j = 0; j < 8; ++j) acc[m][j] = 0.f;

#pragma unroll 1
    for (int kc = 0; kc < 16; ++kc) {
        float4 a[4];
#pragma unroll
        for (int m = 0; m < 4; ++m) a[m] = yt4[(rl + m) * 16 + (kc ^ sa)];
#pragma unroll
        for (int j = 0; j < 8; ++j) {
            int c = c0 + j;
            float4 b = wt4[c * 16 + (kc ^ ((c >> 2) & 15))];
#pragma unroll
            for (int m = 0; m < 4; ++m)
                acc[m][j] += a[m].x * b.x + a[m].y * b.y +
                             a[m].z * b.z + a[m].w * b.w;
        }
    }

#pragma unroll
    for (int m = 0; m < 4; ++m) {
        int row = base + rl + m;
        if (row < n) {
            float dv = dinv[row];
            us8 p;
#pragma unroll
            for (int j = 0; j < 8; ++j) p.v[j] = f2bf(acc[m][j] * dv);
            *(us8*)&hb[((size_t)row << 6) | c0] = p;
        }
    }
}

// ---------- final: out[g] = (pooled[g]/cnt) @ Wout + bout ----------
__global__ void final_out(const float* __restrict__ pooled, const int* __restrict__ cnt,
                          const float* __restrict__ Wout, const float* __restrict__ bout,
                          float* __restrict__ out, int G) {
    int idx = blockIdx.x * blockDim.x + threadIdx.x;
    if (idx >= G * 4) return;
    int g = idx >> 2, o = idx & 3;
    float inv = 1.f / fmaxf((float)cnt[g], 1.f);
    float a = 0.f;
    for (int k = 0; k < 64; ++k) a += pooled[g * 64 + k] * Wout[k * 4 + o];
    out[idx] = a * inv + bout[o];
}

extern "C" void kernel_launch(void* const* d_in, const int* in_sizes, int n_in,
                              void* d_out, int out_size, void* d_ws, size_t ws_size,
                              hipStream_t stream) {
    const int N = in_sizes[0];
    const int E = in_sizes[6] / 2;
    const int T = in_sizes[8] / 64;
    const int G = out_size / 4;

    const int*   type_ids = (const int*)d_in[0];
    const float* fc   = (const float*)d_in[1];
    const float* fgm  = (const float*)d_in[2];
    const float* fpos = (const float*)d_in[3];
    const float* fr   = (const float*)d_in[4];
    const float* fvid = (const float*)d_in[5];
    const int*   ei   = (const int*)d_in[6];
    const int*   batch = (const int*)d_in[7];
    const float* W1 = (const float*)d_in[8];
    const float* b1 = (const float*)d_in[9];
    const float* W2 = (const float*)d_in[10];
    const float* b2 = (const float*)d_in[11];
    const float* Wg0 = (const float*)d_in[12];
    const float* bg0 = (const float*)d_in[13];
    const float* Wg1 = (const float*)d_in[14];
    const float* bg1 = (const float*)d_in[15];
    const float* Wg2 = (const float*)d_in[16];
    const float* bg2 = (const float*)d_in[17];
    const float* gam0 = (const float*)d_in[18];
    const float* bet0 = (const float*)d_in[19];
    const float* gam1 = (const float*)d_in[20];
    const float* bet1 = (const float*)d_in[21];
    const float* Wout = (const float*)d_in[22];
    const float* bout = (const float*)d_in[23];

    const int* e_src = ei;
    const int* e_dst = ei + E;

    // ---- workspace layout ----
    char* ws = (char*)d_ws;
    size_t o = 0;
    auto alloc = [&](size_t bytes) -> char* {
        char* p = ws + o;
        o += (bytes + 255) & ~(size_t)255;
        return p;
    };
    const int NBLK_BN = 256;
    const int NTILES = (N + SCAN_TILE - 1) / SCAN_TILE;
    unsigned short* hb = (unsigned short*)alloc((size_t)(N + 1) * 64 * 2); // +1 zero row
    float* y        = (float*)alloc((size_t)N * 64 * 4);
    int*   deg      = (int*)alloc((size_t)N * 4);
    float* dinv     = (float*)alloc((size_t)N * 4);
    int*   off      = (int*)alloc((size_t)(N + 1) * 4);
    int*   cursor   = (int*)alloc((size_t)N * 4);
    int*   loc      = (int*)alloc((size_t)N * 4);
    int*   tilesum  = (int*)alloc((size_t)NTILES * 4);
    int*   tileoff  = (int*)alloc((size_t)NTILES * 4);
    unsigned short* csrBuf = (unsigned short*)alloc(((size_t)E + 48) * 2);
    unsigned short* csr_u  = csrBuf + 1;   // front pad: csr_u[-1] valid
    unsigned* bucketed = (unsigned*)alloc((size_t)E * 4);
    int*   bkt_cursor  = (int*)alloc(NB * 4);
    int*   go       = (int*)alloc((size_t)(G + 1) * 4);
    float* part0    = (float*)alloc((size_t)NBLK_BN * 128 * 4);
    float* part1    = (float*)alloc((size_t)NBLK_BN * 128 * 4);
    float* scsh0    = (float*)alloc(128 * 4);
    float* scsh1    = (float*)alloc(128 * 4);
    float* pooled   = (float*)alloc((size_t)G * 64 * 4);
    int*   cnt      = (int*)alloc((size_t)G * 4);
    float* M1       = (float*)alloc((size_t)T * 64 * 4);
    float* M2       = (float*)alloc(5 * 64 * 4);
    float* cvec     = (float*)alloc(64 * 4);
    (void)ws_size;

    hipMemsetAsync(deg, 0, (size_t)N * 4, stream);
    hipMemsetAsync(csrBuf, 0, 2, stream);             // front pad entry
    hipMemsetAsync(csr_u + E, 0, 40 * 2, stream);     // tail pad (40 entries)
    hipMemsetAsync(hb + (size_t)N * 64, 0, 128, stream);  // zero row N (mask target)
    hipMemsetAsync(pooled, 0, (size_t)G * 64 * 4, stream);

    const int waves_per_blk = 4;                   // 256 threads
    const int nblk_nodes = (N + waves_per_blk - 1) / waves_per_blk;
    const int nblk_gemm = (N + 127) / 128;
    const int nb_used = (N + 1023) >> 10;          // actual buckets in use

    // graph structure (dinv needed by node_embed)
    count_deg<<<(E + 255) / 256, 256, 0, stream>>>(e_dst, deg, E);
    scan_local<<<NTILES, SCAN_TILE, 0, stream>>>(deg, loc, tilesum, dinv, N);
    scan_tiles<<<1, 64, 0, stream>>>(tilesum, tileoff, NTILES);
    scan_add<<<(N + 255) / 256, 256, 0, stream>>>(loc, tileoff, off, cursor, N);
    init_buckets<<<1, 64, 0, stream>>>(off, bkt_cursor, N);
    bucket_edges<<<(E + EPB - 1) / EPB, 256, 0, stream>>>(e_src, e_dst, bkt_cursor,
                                                          bucketed, E);
    scatter_csr<<<nb_used * SCAT_SLICES, 256, 0, stream>>>(bucketed, off, cursor, csr_u, N);
    build_graph_off<<<(N + 255) / 256, 256, 0, stream>>>(batch, go, N, G);

    precompute_mats<<<1, 256, 0, stream>>>(W1, b1, W2, b2, Wg0, M1, M2, cvec, T);
    node_embed<<<nblk_nodes, 256, 0, stream>>>(type_ids, fc, fgm, fpos, fr, fvid,
                                               M1, M2, cvec, dinv, hb, N);

    // layer 0
    conv_gather<<<nblk_nodes, 256, 0, stream>>>(hb, off, csr_u, dinv, bg0, y, N);
    bn_stats<<<NBLK_BN, 256, 0, stream>>>(y, part0, N);
    bn_finalize<<<1, 1024, 0, stream>>>(part0, NBLK_BN, gam0, bet0, scsh0, N);
    bn_relu_gemm<<<nblk_gemm, 256, 0, stream>>>(y, scsh0, Wg1, dinv, hb, N);

    // layer 1
    conv_gather<<<nblk_nodes, 256, 0, stream>>>(hb, off, csr_u, dinv, bg1, y, N);
    bn_stats<<<NBLK_BN, 256, 0, stream>>>(y, part1, N);
    bn_finalize<<<1, 1024, 0, stream>>>(part1, NBLK_BN, gam1, bet1, scsh1, N);
    bn_relu_gemm<<<nblk_gemm, 256, 0, stream>>>(y, scsh1, Wg2, dinv, hb, N);

    // layer 2: conv + relu + graph-sliced mean-pool
    {
        int waves = G * POOL_SLICES;
        int blocks = (waves + waves_per_blk - 1) / waves_per_blk;
        conv_relu_pool<<<blocks, 256, 0, stream>>>(hb, off, csr_u, dinv, bg2, go,
                                                   pooled, cnt, N, G);
    }

    final_out<<<(G * 4 + 255) / 256, 256, 0, stream>>>(pooled, cnt, Wout, bout, (float*)d_out, G);
}